// Round 1
// baseline (332.304 us; speedup 1.0000x reference)
//
#include <hip/hip_runtime.h>
#include <math.h>

#define BB 1024
#define NN 512
#define MM 256
#define OUTROW (NN + MM + NN * MM)   // 131840
#define EPS_ADD 1e-16f
#define EPS_COS 1e-8f

__device__ inline float waveReduceSum(float v) {
#pragma unroll
    for (int off = 32; off > 0; off >>= 1) v += __shfl_xor(v, off);
    return v;
}
__device__ inline float waveReduceMax(float v) {
#pragma unroll
    for (int off = 32; off > 0; off >>= 1) v = fmaxf(v, __shfl_xor(v, off));
    return v;
}

__global__ __launch_bounds__(512, 4) void ntm_memory_kernel(
    const float* __restrict__ memory, const float* __restrict__ key,
    const float* __restrict__ beta, const float* __restrict__ g,
    const float* __restrict__ s, const float* __restrict__ gamma,
    const float* __restrict__ w_prev, const float* __restrict__ e,
    const float* __restrict__ a, float* __restrict__ out) {
    const int b    = blockIdx.x;
    const int t    = threadIdx.x;
    const int lane = t & 63;
    const int wave = t >> 6;          // 0..7

    __shared__ float key_lds[MM];     // key + eps
    __shared__ float sc[NN];          // scores
    __shared__ float wg[NN];          // gated weights (conv input)
    __shared__ float wf[NN];          // final w
    __shared__ float ea_lds[2 * MM];  // [e | a]
    __shared__ float red[8];
    __shared__ float rpart[8][MM];    // r partials, 8 KB

    const float* __restrict__ memb = memory + (size_t)b * NN * MM;
    float* __restrict__ outb       = out + (size_t)b * OUTROW;

    // ---- stage key (+eps), e, a ----
    if (t < MM) {
        key_lds[t]      = key[b * MM + t] + EPS_ADD;
        ea_lds[MM + t]  = a[b * MM + t];
    } else {
        const int i = t - MM;
        ea_lds[i] = e[b * MM + i];
    }
    __syncthreads();

    // ---- key norm (threads 0..255, 4 waves) ----
    if (t < MM) {
        float kv = key_lds[t];
        float ss = waveReduceSum(kv * kv);
        if (lane == 0) red[wave] = ss;
    }
    __syncthreads();
    const float kn  = fmaxf(sqrtf(red[0] + red[1] + red[2] + red[3]), EPS_COS);
    const float bet = beta[b];
    const float gv  = g[b];
    const float gam = gamma[b];
    const float s0  = s[b * 3 + 0];
    const float s1  = s[b * 3 + 1];
    const float s2  = s[b * 3 + 2];
    __syncthreads();   // red about to be reused

    // ---- phase 1: cosine scores (each wave owns rows n ≡ wave mod 8) ----
    {
        const int col = lane * 4;
        const float4 kv = *reinterpret_cast<const float4*>(&key_lds[col]);
        for (int n = wave; n < NN; n += 8) {
            const float4 mv = *reinterpret_cast<const float4*>(memb + n * MM + col);
            const float mx = mv.x + EPS_ADD, my = mv.y + EPS_ADD;
            const float mz = mv.z + EPS_ADD, mw = mv.w + EPS_ADD;
            float dot = mx * kv.x + my * kv.y + mz * kv.z + mw * kv.w;
            float ss  = mx * mx + my * my + mz * mz + mw * mw;
            dot = waveReduceSum(dot);
            ss  = waveReduceSum(ss);
            if (lane == 0) {
                const float rn = fmaxf(sqrtf(ss), EPS_COS);
                sc[n] = bet * dot / (rn * kn);
            }
        }
    }
    __syncthreads();

    // ---- softmax over N=512 (thread t owns element t) ----
    const float v = sc[t];
    {
        float m1 = waveReduceMax(v);
        if (lane == 0) red[wave] = m1;
    }
    __syncthreads();
    float mmax = red[0];
#pragma unroll
    for (int k = 1; k < 8; k++) mmax = fmaxf(mmax, red[k]);
    const float ex = expf(v - mmax);
    __syncthreads();   // done reading red (max)
    {
        float s1w = waveReduceSum(ex);
        if (lane == 0) red[wave] = s1w;
    }
    __syncthreads();
    float esum = 0.f;
#pragma unroll
    for (int k = 0; k < 8; k++) esum += red[k];
    const float w_c = ex / esum;

    // ---- gate + circular conv + sharpen ----
    wg[t] = gv * w_c + (1.f - gv) * w_prev[b * NN + t];
    __syncthreads();
    const float wt = wg[(t + NN - 1) & (NN - 1)] * s0 + wg[t] * s1 +
                     wg[(t + 1) & (NN - 1)] * s2;
    const float wp = powf(wt, gam);
    __syncthreads();   // done reading red (sum)
    {
        float sw = waveReduceSum(wp);
        if (lane == 0) red[wave] = sw;
    }
    __syncthreads();
    float wsum = 0.f;
#pragma unroll
    for (int k = 0; k < 8; k++) wsum += red[k];
    const float wv = wp / (wsum + EPS_ADD);
    wf[t]   = wv;
    outb[t] = wv;      // output w
    __syncthreads();

    // ---- phase 2: read r + write new_mem ----
    {
        const int col = lane * 4;
        const float4 ev = *reinterpret_cast<const float4*>(&ea_lds[col]);
        const float4 av = *reinterpret_cast<const float4*>(&ea_lds[MM + col]);
        float4 acc = make_float4(0.f, 0.f, 0.f, 0.f);
        for (int nb = 0; nb < NN; nb += 8) {
            const int n = nb + wave;
            const float wn = wf[n];
            const float4 mv = *reinterpret_cast<const float4*>(memb + n * MM + col);
            float4 nm;
            nm.x = mv.x * (1.f - wn * ev.x) + wn * av.x;
            nm.y = mv.y * (1.f - wn * ev.y) + wn * av.y;
            nm.z = mv.z * (1.f - wn * ev.z) + wn * av.z;
            nm.w = mv.w * (1.f - wn * ev.w) + wn * av.w;
            *reinterpret_cast<float4*>(outb + (NN + MM) + n * MM + col) = nm;
            acc.x += wn * mv.x;
            acc.y += wn * mv.y;
            acc.z += wn * mv.z;
            acc.w += wn * mv.w;
        }
        *reinterpret_cast<float4*>(&rpart[wave][col]) = acc;
    }
    __syncthreads();
    if (t < MM) {
        float rsum = 0.f;
#pragma unroll
        for (int k = 0; k < 8; k++) rsum += rpart[k][t];
        outb[NN + t] = rsum;   // output r
    }
}

extern "C" void kernel_launch(void* const* d_in, const int* in_sizes, int n_in,
                              void* d_out, int out_size, void* d_ws, size_t ws_size,
                              hipStream_t stream) {
    const float* memory = (const float*)d_in[0];
    const float* key    = (const float*)d_in[1];
    const float* beta   = (const float*)d_in[2];
    const float* g      = (const float*)d_in[3];
    const float* s      = (const float*)d_in[4];
    const float* gamma  = (const float*)d_in[5];
    const float* w_prev = (const float*)d_in[6];
    const float* e      = (const float*)d_in[7];
    const float* a      = (const float*)d_in[8];
    float* out = (float*)d_out;

    ntm_memory_kernel<<<BB, 512, 0, stream>>>(memory, key, beta, g, s, gamma,
                                              w_prev, e, a, out);
}

// Round 2
// 298.376 us; speedup vs baseline: 1.1137x; 1.1137x over previous
//
#include <hip/hip_runtime.h>
#include <math.h>

#define BB 1024
#define NN 512
#define MM 256
#define OUTROW (NN + MM + NN * MM)   // 131840
#define EPS_ADD 1e-16f
#define EPS_COS 1e-8f

typedef float f4v __attribute__((ext_vector_type(4)));

__device__ inline float waveReduceSum(float v) {
#pragma unroll
    for (int off = 32; off > 0; off >>= 1) v += __shfl_xor(v, off);
    return v;
}
__device__ inline float waveReduceMax(float v) {
#pragma unroll
    for (int off = 32; off > 0; off >>= 1) v = fmaxf(v, __shfl_xor(v, off));
    return v;
}

__global__ __launch_bounds__(512, 4) void ntm_memory_kernel(
    const float* __restrict__ memory, const float* __restrict__ key,
    const float* __restrict__ beta, const float* __restrict__ g,
    const float* __restrict__ s, const float* __restrict__ gamma,
    const float* __restrict__ w_prev, const float* __restrict__ e,
    const float* __restrict__ a, float* __restrict__ out) {
    const int b    = blockIdx.x;
    const int t    = threadIdx.x;
    const int lane = t & 63;
    const int wave = t >> 6;          // 0..7

    __shared__ float key_lds[MM];     // key + eps
    __shared__ float sc[NN];          // scores
    __shared__ float wg[NN];          // gated weights (conv input)
    __shared__ float wf[NN];          // final w
    __shared__ float ea_lds[2 * MM];  // [e | a]
    __shared__ float red[8];
    __shared__ float rpart[8][MM];    // r partials, 8 KB

    const float* __restrict__ memb = memory + (size_t)b * NN * MM;
    float* __restrict__ outb       = out + (size_t)b * OUTROW;

    // ---- stage key (+eps), e, a ----
    if (t < MM) {
        key_lds[t]      = key[b * MM + t] + EPS_ADD;
        ea_lds[MM + t]  = a[b * MM + t];
    } else {
        const int i = t - MM;
        ea_lds[i] = e[b * MM + i];
    }
    __syncthreads();

    // ---- key norm (threads 0..255, 4 waves) ----
    if (t < MM) {
        float kv = key_lds[t];
        float ss = waveReduceSum(kv * kv);
        if (lane == 0) red[wave] = ss;
    }
    __syncthreads();
    const float kn  = fmaxf(sqrtf(red[0] + red[1] + red[2] + red[3]), EPS_COS);
    const float bet = beta[b];
    const float gv  = g[b];
    const float gam = gamma[b];
    const float s0  = s[b * 3 + 0];
    const float s1  = s[b * 3 + 1];
    const float s2  = s[b * 3 + 2];
    __syncthreads();   // red about to be reused

    // ---- phase 1: cosine scores. 16 lanes per row, 4 rows per wave-iter ----
    {
        const int sub = lane >> 4;    // 0..3  (row within group)
        const int sl  = lane & 15;    // 0..15 (16 lanes share a row)
        // preload key fragments for this lane's columns (4 m-chunks of 64)
        f4v kf[4];
#pragma unroll
        for (int mc = 0; mc < 4; mc++)
            kf[mc] = *reinterpret_cast<const f4v*>(&key_lds[mc * 64 + sl * 4]);

        const int rbase = wave * 64;
        for (int gi = 0; gi < 16; ++gi) {
            const int r = rbase + gi * 4 + sub;
            const float* __restrict__ rp = memb + r * MM + sl * 4;
            float dot = 0.f, ss = 0.f;
#pragma unroll
            for (int mc = 0; mc < 4; ++mc) {
                const f4v mv = *reinterpret_cast<const f4v*>(rp + mc * 64);
                const float mx = mv.x + EPS_ADD, my = mv.y + EPS_ADD;
                const float mz = mv.z + EPS_ADD, mw = mv.w + EPS_ADD;
                dot += mx * kf[mc].x + my * kf[mc].y + mz * kf[mc].z + mw * kf[mc].w;
                ss  += mx * mx + my * my + mz * mz + mw * mw;
            }
#pragma unroll
            for (int off = 8; off > 0; off >>= 1) {
                dot += __shfl_xor(dot, off);
                ss  += __shfl_xor(ss, off);
            }
            if (sl == 0) {
                sc[r] = bet * dot / (fmaxf(sqrtf(ss), EPS_COS) * kn);
            }
        }
    }
    __syncthreads();

    // ---- softmax over N=512 (thread t owns element t) ----
    const float v = sc[t];
    {
        float m1 = waveReduceMax(v);
        if (lane == 0) red[wave] = m1;
    }
    __syncthreads();
    float mmax = red[0];
#pragma unroll
    for (int k = 1; k < 8; k++) mmax = fmaxf(mmax, red[k]);
    const float ex = expf(v - mmax);
    __syncthreads();   // done reading red (max)
    {
        float s1w = waveReduceSum(ex);
        if (lane == 0) red[wave] = s1w;
    }
    __syncthreads();
    float esum = 0.f;
#pragma unroll
    for (int k = 0; k < 8; k++) esum += red[k];
    const float w_c = ex / esum;

    // ---- gate + circular conv + sharpen ----
    wg[t] = gv * w_c + (1.f - gv) * w_prev[b * NN + t];
    __syncthreads();
    const float wt = wg[(t + NN - 1) & (NN - 1)] * s0 + wg[t] * s1 +
                     wg[(t + 1) & (NN - 1)] * s2;
    const float wp = powf(wt, gam);
    __syncthreads();   // done reading red (sum)
    {
        float sw = waveReduceSum(wp);
        if (lane == 0) red[wave] = sw;
    }
    __syncthreads();
    float wsum = 0.f;
#pragma unroll
    for (int k = 0; k < 8; k++) wsum += red[k];
    const float wv = wp / (wsum + EPS_ADD);
    wf[t]   = wv;
    outb[t] = wv;      // output w
    __syncthreads();

    // ---- phase 2: read r + write new_mem (unrolled, nt stores) ----
    {
        const int col = lane * 4;
        const f4v ev = *reinterpret_cast<const f4v*>(&ea_lds[col]);
        const f4v av = *reinterpret_cast<const f4v*>(&ea_lds[MM + col]);
        f4v acc = (f4v)0.f;
#pragma unroll 4
        for (int nb = 0; nb < NN; nb += 8) {
            const int n = nb + wave;
            const float wn = wf[n];
            const f4v mv = *reinterpret_cast<const f4v*>(memb + n * MM + col);
            f4v nm;
            nm.x = mv.x * (1.f - wn * ev.x) + wn * av.x;
            nm.y = mv.y * (1.f - wn * ev.y) + wn * av.y;
            nm.z = mv.z * (1.f - wn * ev.z) + wn * av.z;
            nm.w = mv.w * (1.f - wn * ev.w) + wn * av.w;
            __builtin_nontemporal_store(nm,
                reinterpret_cast<f4v*>(outb + (NN + MM) + n * MM + col));
            acc.x += wn * mv.x;
            acc.y += wn * mv.y;
            acc.z += wn * mv.z;
            acc.w += wn * mv.w;
        }
        *reinterpret_cast<f4v*>(&rpart[wave][col]) = acc;
    }
    __syncthreads();
    if (t < MM) {
        float rsum = 0.f;
#pragma unroll
        for (int k = 0; k < 8; k++) rsum += rpart[k][t];
        outb[NN + t] = rsum;   // output r
    }
}

extern "C" void kernel_launch(void* const* d_in, const int* in_sizes, int n_in,
                              void* d_out, int out_size, void* d_ws, size_t ws_size,
                              hipStream_t stream) {
    const float* memory = (const float*)d_in[0];
    const float* key    = (const float*)d_in[1];
    const float* beta   = (const float*)d_in[2];
    const float* g      = (const float*)d_in[3];
    const float* s      = (const float*)d_in[4];
    const float* gamma  = (const float*)d_in[5];
    const float* w_prev = (const float*)d_in[6];
    const float* e      = (const float*)d_in[7];
    const float* a      = (const float*)d_in[8];
    float* out = (float*)d_out;

    ntm_memory_kernel<<<BB, 512, 0, stream>>>(memory, key, beta, g, s, gamma,
                                              w_prev, e, a, out);
}